// Round 7
// baseline (2370.006 us; speedup 1.0000x reference)
//
#include <hip/hip_runtime.h>
#include <hip/hip_bf16.h>
#include <math.h>

// Problem constants (match reference)
#define ND 16
#define ED 8
#define HD 5
#define NG 256
#define EPS_GN 1e-5f

#define BUCKET_SHIFT 7                 // 128 nodes per bucket
#define BUCKET_NODES 128
#define NB_MAX 1600                    // cap for static LDS (N<=204800)
#define NBLK 2048                      // chunks for hist/build partition
#define SCAN_PER (NBLK / 256)          // values per thread in scan_blocks

// ---------------------------------------------------------------------------
// HW float atomic wrapper (used only in fallback path)
// ---------------------------------------------------------------------------
__device__ inline void atomAdd(float* p, float v) {
#if __has_builtin(__builtin_amdgcn_flat_atomic_fadd_f32)
  __builtin_amdgcn_flat_atomic_fadd_f32(p, v);
#elif __has_builtin(__builtin_amdgcn_global_atomic_fadd_f32)
  __builtin_amdgcn_global_atomic_fadd_f32((__attribute__((address_space(1))) float*)p, v);
#else
  atomicAdd(p, v);
#endif
}

// ===========================================================================
// SORT PATH (no global float atomics)
// record split (R4): rec1 = {key, p[5]} 24B, rec2 = {key, c2[5]} 24B
// key = (src << 7) | (dst & 127); src < 2^25 always (int node ids)
// ===========================================================================

// --- 1. per-block bucket histogram --------------------------------------
__global__ __launch_bounds__(256) void hist_kernel(
    const int* __restrict__ dstp, int* __restrict__ offs,
    long E, int NB, long chunk) {
  __shared__ int sh[NB_MAX];
  int tid = threadIdx.x;
  for (int j = tid; j < NB; j += 256) sh[j] = 0;
  __syncthreads();
  long e0 = (long)blockIdx.x * chunk;
  long e1 = e0 + chunk; if (e1 > E) e1 = E;
  for (long e = e0 + tid; e < e1; e += 256)
    atomicAdd(&sh[dstp[e] >> BUCKET_SHIFT], 1);
  __syncthreads();
  size_t base = (size_t)blockIdx.x * NB;
  for (int j = tid; j < NB; j += 256) offs[base + j] = sh[j];
}

// --- 2a. PARALLEL per-bucket exclusive scan over blocks ------------------
__global__ __launch_bounds__(256) void scan_blocks(
    int* __restrict__ offs, int* __restrict__ btot, int NB) {
  int j = blockIdx.x;
  int t = threadIdx.x;
  __shared__ int tsum[256];
  int loc[SCAN_PER];
  int s = 0;
#pragma unroll
  for (int i = 0; i < SCAN_PER; ++i) {
    int b = t * SCAN_PER + i;
    int v = offs[(size_t)b * NB + j];
    loc[i] = s;
    s += v;
  }
  tsum[t] = s;
  __syncthreads();
  for (int off = 1; off < 256; off <<= 1) {
    int v = (t >= off) ? tsum[t - off] : 0;
    __syncthreads();
    tsum[t] += v;
    __syncthreads();
  }
  int base = (t > 0) ? tsum[t - 1] : 0;
#pragma unroll
  for (int i = 0; i < SCAN_PER; ++i) {
    int b = t * SCAN_PER + i;
    offs[(size_t)b * NB + j] = base + loc[i];
  }
  if (t == 255) btot[j] = tsum[255];
}

// --- 2b. exclusive scan of bucket totals (single block) ------------------
__global__ __launch_bounds__(256) void scanB(
    const int* __restrict__ btot, int* __restrict__ bbase, int NB) {
  __shared__ int tsum[256];
  int t = threadIdx.x;
  int loc[8];
  int s = 0;
#pragma unroll
  for (int i = 0; i < 8; ++i) {
    int idx = t * 8 + i;
    int v = (idx < NB) ? btot[idx] : 0;
    loc[i] = s;
    s += v;
  }
  tsum[t] = s;
  __syncthreads();
  for (int off = 1; off < 256; off <<= 1) {
    int v = (t >= off) ? tsum[t - off] : 0;
    __syncthreads();
    tsum[t] += v;
    __syncthreads();
  }
  int base = (t > 0) ? tsum[t - 1] : 0;
#pragma unroll
  for (int i = 0; i < 8; ++i) {
    int idx = t * 8 + i;
    if (idx < NB) bbase[idx] = base + loc[i];
  }
}

// --- 3. streaming edge pass ----------------------------------------------
// Computes c2 = W2e@ea+b2e (stored to rec2 early, overlapping the x gather),
// then p = Wn1@relu(x[src]+W1e@ea+b1e) (stored to rec1).
// __launch_bounds__(256,4): cap VGPR at 128 -> 16 waves/CU for latency hiding.
__global__ __launch_bounds__(256, 4) void build_scatter(
    const float* __restrict__ ea, const int* __restrict__ srcp,
    const int* __restrict__ dstp, const float* __restrict__ x,
    const float* __restrict__ W1e, const float* __restrict__ b1e,
    const float* __restrict__ Wn1, const float* __restrict__ W2e,
    const float* __restrict__ b2e,
    const int* __restrict__ offs, const int* __restrict__ bbase,
    float* __restrict__ rec1, float* __restrict__ rec2,
    long E, int NB, long chunk) {
  __shared__ int cur[NB_MAX];
  __shared__ float swt[272];  // [0,128) W1e | [128,144) b1e | [144,224) Wn1
                              // [224,264) W2e | [264,269) b2e
  int tid = threadIdx.x;
  if (tid < 128) swt[tid] = W1e[tid];
  if (tid < 16) swt[128 + tid] = b1e[tid];
  if (tid < 80) swt[144 + tid] = Wn1[tid];
  if (tid < 40) swt[224 + tid] = W2e[tid];
  if (tid < 5) swt[264 + tid] = b2e[tid];
  size_t obase = (size_t)blockIdx.x * NB;
  for (int j = tid; j < NB; j += 256) cur[j] = offs[obase + j] + bbase[j];
  __syncthreads();

  const float4* ea4 = reinterpret_cast<const float4*>(ea);
  long e0 = (long)blockIdx.x * chunk;
  long e1 = e0 + chunk; if (e1 > E) e1 = E;

  for (long e = e0 + tid; e < e1; e += 256) {
    // issue all loads up front
    float4 a0 = ea4[2 * e];
    float4 a1 = ea4[2 * e + 1];
    int s = srcp[e];
    int d = dstp[e];
    const float4* xr = reinterpret_cast<const float4*>(x + (size_t)s * ND);
    float4 x0 = xr[0], x1 = xr[1], x2 = xr[2], x3 = xr[3];

    float av[ED] = {a0.x, a0.y, a0.z, a0.w, a1.x, a1.y, a1.z, a1.w};
    unsigned key = ((unsigned)s << BUCKET_SHIFT) | (unsigned)(d & (BUCKET_NODES - 1));

    // c2 first (only needs av) — overlaps x-gather latency
    float c2[HD];
#pragma unroll
    for (int q = 0; q < HD; ++q) {
      float m = swt[264 + q];
#pragma unroll
      for (int k = 0; k < ED; ++k) m += swt[224 + q * ED + k] * av[k];
      c2[q] = m;
    }
    int bkt = d >> BUCKET_SHIFT;
    int pos = atomicAdd(&cur[bkt], 1);
    float2* r2 = reinterpret_cast<float2*>(rec2 + (size_t)pos * 6);
    r2[0] = make_float2(__uint_as_float(key), c2[0]);
    r2[1] = make_float2(c2[1], c2[2]);
    r2[2] = make_float2(c2[3], c2[4]);

    // p (needs x gather)
    float xv[ND] = {x0.x, x0.y, x0.z, x0.w, x1.x, x1.y, x1.z, x1.w,
                    x2.x, x2.y, x2.z, x2.w, x3.x, x3.y, x3.z, x3.w};
    float p[HD] = {0.f, 0.f, 0.f, 0.f, 0.f};
#pragma unroll
    for (int j = 0; j < ND; ++j) {
      float m = swt[128 + j];
#pragma unroll
      for (int k = 0; k < ED; ++k) m += swt[j * ED + k] * av[k];
      m = fmaxf(m + xv[j], 0.f);
#pragma unroll
      for (int q = 0; q < HD; ++q) p[q] += m * swt[144 + q * ND + j];
    }
    float2* r1 = reinterpret_cast<float2*>(rec1 + (size_t)pos * 6);
    r1[0] = make_float2(__uint_as_float(key), p[0]);
    r1[1] = make_float2(p[1], p[2]);
    r1[2] = make_float2(p[3], p[4]);
  }
}

// --- 4. bucket reduce pass 1 (+ fused node pass 1) -----------------------
__global__ __launch_bounds__(256) void reduce1(
    const float* __restrict__ rec1, const int* __restrict__ bbase,
    const int* __restrict__ btot, const float* __restrict__ x,
    const float* __restrict__ Wn1, const float* __restrict__ bn1,
    const float* __restrict__ eps1p, float* __restrict__ h1, int N) {
  __shared__ float acc[BUCKET_NODES * HD];  // 640
  __shared__ float sWn1[80];
  __shared__ float sbn1[HD];
  __shared__ float seps;
  int tid = threadIdx.x;
  int j = blockIdx.x;
  if (tid < 80) sWn1[tid] = Wn1[tid];
  if (tid < HD) sbn1[tid] = bn1[tid];
  if (tid == 0) seps = 1.0f + eps1p[0];
  for (int i = tid; i < BUCKET_NODES * HD; i += 256) acc[i] = 0.f;
  __syncthreads();

  int nbase = j << BUCKET_SHIFT;
  int lo = bbase[j], hi = lo + btot[j];
  for (int i = lo + tid; i < hi; i += 256) {
    const float2* r = reinterpret_cast<const float2*>(rec1 + (size_t)i * 6);
    float2 v0 = r[0], v1 = r[1], v2 = r[2];
    int dl = (int)(__float_as_uint(v0.x) & (BUCKET_NODES - 1));
    atomicAdd(&acc[dl * HD + 0], v0.y);
    atomicAdd(&acc[dl * HD + 1], v1.x);
    atomicAdd(&acc[dl * HD + 2], v1.y);
    atomicAdd(&acc[dl * HD + 3], v2.x);
    atomicAdd(&acc[dl * HD + 4], v2.y);
  }
  __syncthreads();

  for (int t = tid; t < BUCKET_NODES * HD; t += 256) {
    int node = nbase + t / HD;
    int q = t - (t / HD) * HD;
    if (node < N) {
      const float* xr = x + (size_t)node * ND;
      float dot = 0.f;
#pragma unroll
      for (int k = 0; k < ND; ++k) dot += sWn1[q * ND + k] * xr[k];
      h1[(size_t)node * HD + q] = seps * dot + acc[t] + sbn1[q];
    }
  }
}

// --- 5. GraphNorm + ReLU (one block per graph) ---------------------------
__global__ __launch_bounds__(256) void graphnorm_pass(
    const float* __restrict__ h1, const int* __restrict__ batch,
    const float* __restrict__ w, const float* __restrict__ b,
    const float* __restrict__ ms, float* __restrict__ hn, int N) {
  int g = blockIdx.x;
  __shared__ int s_lo, s_hi;
  __shared__ float s_red[4][HD];
  __shared__ float s_mean[HD];
  __shared__ float s_scale[HD];
  if (threadIdx.x == 0) {
    int lo = 0, hi = N;
    while (lo < hi) { int mid = (lo + hi) >> 1; if (batch[mid] < g) lo = mid + 1; else hi = mid; }
    s_lo = lo;
    hi = N;
    while (lo < hi) { int mid = (lo + hi) >> 1; if (batch[mid] < g + 1) lo = mid + 1; else hi = mid; }
    s_hi = lo;
  }
  __syncthreads();
  int lo = s_lo, hi = s_hi;
  int cnt = hi - lo;
  float rc = 1.0f / fmaxf((float)cnt, 1.0f);
  int wid = threadIdx.x >> 6;
  int lane = threadIdx.x & 63;

  float acc[HD] = {0.f, 0.f, 0.f, 0.f, 0.f};
  for (int i = lo + threadIdx.x; i < hi; i += blockDim.x) {
#pragma unroll
    for (int q = 0; q < HD; ++q) acc[q] += h1[(size_t)i * HD + q];
  }
#pragma unroll
  for (int q = 0; q < HD; ++q)
    for (int off = 32; off > 0; off >>= 1) acc[q] += __shfl_down(acc[q], off);
  if (lane == 0)
#pragma unroll
    for (int q = 0; q < HD; ++q) s_red[wid][q] = acc[q];
  __syncthreads();
  if (threadIdx.x == 0) {
#pragma unroll
    for (int q = 0; q < HD; ++q)
      s_mean[q] = (s_red[0][q] + s_red[1][q] + s_red[2][q] + s_red[3][q]) * rc * ms[q];
  }
  __syncthreads();

#pragma unroll
  for (int q = 0; q < HD; ++q) acc[q] = 0.f;
  for (int i = lo + threadIdx.x; i < hi; i += blockDim.x) {
#pragma unroll
    for (int q = 0; q < HD; ++q) {
      float s = h1[(size_t)i * HD + q] - s_mean[q];
      acc[q] += s * s;
    }
  }
#pragma unroll
  for (int q = 0; q < HD; ++q)
    for (int off = 32; off > 0; off >>= 1) acc[q] += __shfl_down(acc[q], off);
  if (lane == 0)
#pragma unroll
    for (int q = 0; q < HD; ++q) s_red[wid][q] = acc[q];
  __syncthreads();
  if (threadIdx.x == 0) {
#pragma unroll
    for (int q = 0; q < HD; ++q) {
      float var = (s_red[0][q] + s_red[1][q] + s_red[2][q] + s_red[3][q]) * rc;
      s_scale[q] = w[q] * rsqrtf(var + EPS_GN);
    }
  }
  __syncthreads();

  for (int i = lo + threadIdx.x; i < hi; i += blockDim.x) {
#pragma unroll
    for (int q = 0; q < HD; ++q) {
      float s = h1[(size_t)i * HD + q] - s_mean[q];
      hn[(size_t)i * HD + q] = fmaxf(s * s_scale[q] + b[q], 0.f);
    }
  }
}

// --- 6. bucket reduce pass 2 (+ fused sigmoid epilogue) ------------------
__global__ __launch_bounds__(256) void reduce2(
    const float* __restrict__ rec2, const int* __restrict__ bbase,
    const int* __restrict__ btot, const float* __restrict__ hn,
    const float* __restrict__ Wn2, const float* __restrict__ bn2,
    const float* __restrict__ eps2p, float* __restrict__ out, int N) {
  __shared__ float acc[BUCKET_NODES];
  __shared__ float sP[HD];
  __shared__ float sb, seps;
  int tid = threadIdx.x;
  int j = blockIdx.x;
  if (tid < HD) sP[tid] = Wn2[tid];
  if (tid == 0) { sb = bn2[0]; seps = 1.0f + eps2p[0]; }
  if (tid < BUCKET_NODES) acc[tid] = 0.f;
  __syncthreads();

  int nbase = j << BUCKET_SHIFT;
  int lo = bbase[j], hi = lo + btot[j];
  for (int i = lo + tid; i < hi; i += 256) {
    const float2* r = reinterpret_cast<const float2*>(rec2 + (size_t)i * 6);
    float2 v0 = r[0], v1 = r[1], v2 = r[2];
    unsigned key = __float_as_uint(v0.x);
    int dl = (int)(key & (BUCKET_NODES - 1));
    int s = (int)(key >> BUCKET_SHIFT);
    const float* hr = hn + (size_t)s * HD;
    float v = sP[0] * fmaxf(hr[0] + v0.y, 0.f)
            + sP[1] * fmaxf(hr[1] + v1.x, 0.f)
            + sP[2] * fmaxf(hr[2] + v1.y, 0.f)
            + sP[3] * fmaxf(hr[3] + v2.x, 0.f)
            + sP[4] * fmaxf(hr[4] + v2.y, 0.f);
    atomicAdd(&acc[dl], v);
  }
  __syncthreads();

  if (tid < BUCKET_NODES) {
    int node = nbase + tid;
    if (node < N) {
      const float* hr = hn + (size_t)node * HD;
      float z = sb + acc[tid];
#pragma unroll
      for (int q = 0; q < HD; ++q) z += seps * sP[q] * hr[q];
      out[node] = 1.0f / (1.0f + expf(-z));
    }
  }
}

// ===========================================================================
// FALLBACK PATH (R1 structure, HW-fadd atomics) — used only if ws too small
// ===========================================================================
__global__ __launch_bounds__(256) void edge_pass1(
    const float* __restrict__ ea, const int* __restrict__ ei,
    const float* __restrict__ x,
    const float* __restrict__ W1e, const float* __restrict__ b1e,
    const float* __restrict__ Wn1,
    float* __restrict__ agg1p, long E) {
  __shared__ float sW[ND * ED];
  __shared__ float sB[ND];
  __shared__ float sP[HD * ND];
  int tid = threadIdx.x;
  if (tid < ND * ED) sW[tid] = W1e[tid];
  if (tid < ND) sB[tid] = b1e[tid];
  if (tid < HD * ND) sP[tid] = Wn1[tid];
  __syncthreads();
  const float4* ea4 = reinterpret_cast<const float4*>(ea);
  const int* src = ei;
  const int* dst = ei + E;
  long idx = (long)blockIdx.x * blockDim.x + tid;
  long stride = (long)gridDim.x * blockDim.x;
  for (long e = idx; e < E; e += stride) {
    float4 a0 = ea4[2 * e];
    float4 a1 = ea4[2 * e + 1];
    float av[ED] = {a0.x, a0.y, a0.z, a0.w, a1.x, a1.y, a1.z, a1.w};
    int s = src[e];
    int d = dst[e];
    const float4* xr = reinterpret_cast<const float4*>(x + (size_t)s * ND);
    float4 x0 = xr[0], x1 = xr[1], x2 = xr[2], x3 = xr[3];
    float xv[ND] = {x0.x, x0.y, x0.z, x0.w, x1.x, x1.y, x1.z, x1.w,
                    x2.x, x2.y, x2.z, x2.w, x3.x, x3.y, x3.z, x3.w};
    float p[HD] = {0.f, 0.f, 0.f, 0.f, 0.f};
#pragma unroll
    for (int j = 0; j < ND; ++j) {
      float m = sB[j];
#pragma unroll
      for (int k = 0; k < ED; ++k) m += sW[j * ED + k] * av[k];
      m = fmaxf(m + xv[j], 0.f);
#pragma unroll
      for (int q = 0; q < HD; ++q) p[q] += m * sP[q * ND + j];
    }
    float* ag = agg1p + (size_t)d * HD;
#pragma unroll
    for (int q = 0; q < HD; ++q) atomAdd(ag + q, p[q]);
  }
}

__global__ __launch_bounds__(256) void node_pass1(
    const float* __restrict__ x, const float* __restrict__ agg1p,
    const float* __restrict__ Wn1, const float* __restrict__ bn1,
    const float* __restrict__ eps1p, float* __restrict__ h1, int N) {
  int n = blockIdx.x * blockDim.x + threadIdx.x;
  if (n >= N) return;
  float e1 = 1.0f + *eps1p;
  const float4* xr = reinterpret_cast<const float4*>(x + (size_t)n * ND);
  float4 x0 = xr[0], x1 = xr[1], x2 = xr[2], x3 = xr[3];
  float xv[ND] = {x0.x, x0.y, x0.z, x0.w, x1.x, x1.y, x1.z, x1.w,
                  x2.x, x2.y, x2.z, x2.w, x3.x, x3.y, x3.z, x3.w};
#pragma unroll
  for (int q = 0; q < HD; ++q) {
    float acc = 0.f;
#pragma unroll
    for (int j = 0; j < ND; ++j) acc += Wn1[q * ND + j] * xv[j];
    h1[(size_t)n * HD + q] = e1 * acc + agg1p[(size_t)n * HD + q] + bn1[q];
  }
}

__global__ __launch_bounds__(256) void edge_pass2(
    const float* __restrict__ ea, const int* __restrict__ ei,
    const float* __restrict__ hn,
    const float* __restrict__ W2e, const float* __restrict__ b2e,
    const float* __restrict__ Wn2,
    float* __restrict__ agg2s, long E) {
  __shared__ float sW[HD * ED];
  __shared__ float sB[HD];
  __shared__ float sP[HD];
  int tid = threadIdx.x;
  if (tid < HD * ED) sW[tid] = W2e[tid];
  if (tid < HD) sB[tid] = b2e[tid];
  if (tid < HD) sP[tid] = Wn2[tid];
  __syncthreads();
  const float4* ea4 = reinterpret_cast<const float4*>(ea);
  const int* src = ei;
  const int* dst = ei + E;
  long idx = (long)blockIdx.x * blockDim.x + tid;
  long stride = (long)gridDim.x * blockDim.x;
  for (long e = idx; e < E; e += stride) {
    float4 a0 = ea4[2 * e];
    float4 a1 = ea4[2 * e + 1];
    float av[ED] = {a0.x, a0.y, a0.z, a0.w, a1.x, a1.y, a1.z, a1.w};
    int s = src[e];
    int d = dst[e];
    const float* hr = hn + (size_t)s * HD;
    float acc = 0.f;
#pragma unroll
    for (int q = 0; q < HD; ++q) {
      float m = sB[q];
#pragma unroll
      for (int k = 0; k < ED; ++k) m += sW[q * ED + k] * av[k];
      m = fmaxf(m + hr[q], 0.f);
      acc += m * sP[q];
    }
    atomAdd(agg2s + d, acc);
  }
}

__global__ __launch_bounds__(256) void node_pass2(
    const float* __restrict__ hn, const float* __restrict__ agg2s,
    const float* __restrict__ Wn2, const float* __restrict__ bn2,
    const float* __restrict__ eps2p, float* __restrict__ out, int N) {
  int n = blockIdx.x * blockDim.x + threadIdx.x;
  if (n >= N) return;
  float e2 = 1.0f + *eps2p;
  const float* hr = hn + (size_t)n * HD;
  float z = bn2[0] + agg2s[n];
#pragma unroll
  for (int q = 0; q < HD; ++q) z += Wn2[q] * e2 * hr[q];
  out[n] = 1.0f / (1.0f + expf(-z));
}

// ===========================================================================
extern "C" void kernel_launch(void* const* d_in, const int* in_sizes, int n_in,
                              void* d_out, int out_size, void* d_ws, size_t ws_size,
                              hipStream_t stream) {
  const float* x       = (const float*)d_in[0];
  const int*   ei      = (const int*)d_in[1];
  const float* ea      = (const float*)d_in[2];
  const int*   batch   = (const int*)d_in[3];
  const float* eps1    = (const float*)d_in[4];
  const float* W1e     = (const float*)d_in[5];
  const float* b1e     = (const float*)d_in[6];
  const float* Wn1     = (const float*)d_in[7];
  const float* bn1     = (const float*)d_in[8];
  const float* gn_w    = (const float*)d_in[9];
  const float* gn_b    = (const float*)d_in[10];
  const float* gn_ms   = (const float*)d_in[11];
  const float* eps2    = (const float*)d_in[12];
  const float* W2e     = (const float*)d_in[13];
  const float* b2e     = (const float*)d_in[14];
  const float* Wn2     = (const float*)d_in[15];
  const float* bn2     = (const float*)d_in[16];

  const int  N = in_sizes[3];
  const long E = (long)in_sizes[2] / ED;
  const int  NB = (N + BUCKET_NODES - 1) >> BUCKET_SHIFT;
  const size_t NBp = ((size_t)NB + 3) & ~(size_t)3;

  // sort-path workspace (float/int units)
  const size_t recF  = (size_t)E * 12;          // rec1 (6f) + rec2 (6f)
  const size_t offsI = (size_t)NBLK * NB;
  const size_t need  = (recF + offsI + 2 * NBp + 10 * (size_t)N + 64) * 4;

  float* out = (float*)d_out;
  const int* srcp = ei;
  const int* dstp = ei + E;

  if (ws_size >= need && NB <= NB_MAX) {
    // ------------------------- SORT PATH -------------------------
    float* ws    = (float*)d_ws;
    float* rec1  = ws;
    float* rec2  = ws + (size_t)E * 6;
    int*   offs  = (int*)(ws + recF);
    int*   btot  = (int*)(ws + recF + offsI);
    int*   bbase = (int*)(ws + recF + offsI + NBp);
    float* h1    = ws + recF + offsI + 2 * NBp;
    float* hn    = h1 + 5 * (size_t)N;

    const long chunk = (E + NBLK - 1) / NBLK;

    hist_kernel<<<NBLK, 256, 0, stream>>>(dstp, offs, E, NB, chunk);
    scan_blocks<<<NB, 256, 0, stream>>>(offs, btot, NB);
    scanB<<<1, 256, 0, stream>>>(btot, bbase, NB);
    build_scatter<<<NBLK, 256, 0, stream>>>(ea, srcp, dstp, x,
                                            W1e, b1e, Wn1, W2e, b2e,
                                            offs, bbase, rec1, rec2, E, NB, chunk);
    reduce1<<<NB, 256, 0, stream>>>(rec1, bbase, btot, x, Wn1, bn1, eps1, h1, N);
    graphnorm_pass<<<NG, 256, 0, stream>>>(h1, batch, gn_w, gn_b, gn_ms, hn, N);
    reduce2<<<NB, 256, 0, stream>>>(rec2, bbase, btot, hn, Wn2, bn2, eps2, out, N);
  } else {
    // ----------------------- FALLBACK PATH -----------------------
    float* ws     = (float*)d_ws;
    float* agg1p  = ws;
    float* agg2s  = ws + (size_t)N * 5;
    float* h1     = ws + (size_t)N * 6;
    float* hn     = ws + (size_t)N * 11;

    hipMemsetAsync(ws, 0, (size_t)N * 6 * sizeof(float), stream);

    const int TB = 256;
    int edge_blocks = 4096;
    int node_blocks = (N + TB - 1) / TB;

    edge_pass1<<<edge_blocks, TB, 0, stream>>>(ea, ei, x, W1e, b1e, Wn1, agg1p, E);
    node_pass1<<<node_blocks, TB, 0, stream>>>(x, agg1p, Wn1, bn1, eps1, h1, N);
    graphnorm_pass<<<NG, TB, 0, stream>>>(h1, batch, gn_w, gn_b, gn_ms, hn, N);
    edge_pass2<<<edge_blocks, TB, 0, stream>>>(ea, ei, hn, W2e, b2e, Wn2, agg2s, E);
    node_pass2<<<node_blocks, TB, 0, stream>>>(hn, agg2s, Wn2, bn2, eps2, out, N);
  }
}